// Round 1
// baseline (94.905 us; speedup 1.0000x reference)
//
#include <hip/hip_runtime.h>
#include <math.h>

#define NB   16384
#define SEQ  10
#define DIM  8
#define TRIL 36

__device__ __forceinline__ constexpr int tri(int r, int c) { return r * (r + 1) / 2 + c; } // r >= c

// ---- DPP quad-perm helpers (VALU cross-lane within each aligned quad) ----
// ctrl byte = s0 | s1<<2 | s2<<4 | s3<<6 : lane i reads from quad-lane s_i.
template <int CTRL>
__device__ __forceinline__ float fperm(float v) {
    return __int_as_float(__builtin_amdgcn_mov_dpp(__float_as_int(v), CTRL, 0xf, 0xf, true));
}
template <int CTRL>
__device__ __forceinline__ double dperm(double v) {
    long long u = __double_as_longlong(v);
    int lo = (int)(u & 0xffffffffLL);
    int hi = (int)(u >> 32);
    lo = __builtin_amdgcn_mov_dpp(lo, CTRL, 0xf, 0xf, true);
    hi = __builtin_amdgcn_mov_dpp(hi, CTRL, 0xf, 0xf, true);
    return __longlong_as_double(((long long)hi << 32) | (long long)(unsigned)lo);
}
// quad perms: XOR1=[1,0,3,2]=0xB1, XOR2=[2,3,0,1]=0x4E,
// RECV_A: from (g+3)&3 = [3,0,1,2] = 0x93 ; RECV_B: from (g+1)&3 = [1,2,3,0] = 0x39.

// ---- xor-4 cross-quad exchange via ds_swizzle (BitMode: xor_mask=4, and=0x1F) ----
__device__ __forceinline__ float fswz4(float v) {
    return __int_as_float(__builtin_amdgcn_ds_swizzle(__float_as_int(v), 0x101F));
}
__device__ __forceinline__ double dswz4(double v) {
    long long u = __double_as_longlong(v);
    int lo = (int)(u & 0xffffffffLL);
    int hi = (int)(u >> 32);
    lo = __builtin_amdgcn_ds_swizzle(lo, 0x101F);
    hi = __builtin_amdgcn_ds_swizzle(hi, 0x101F);
    return __longlong_as_double(((long long)hi << 32) | (long long)(unsigned)lo);
}

// fp64 rsqrt/rcp via HW seed + Newton (no fp64 div/sqrt chains)
__device__ __forceinline__ double fast_rsqrt(double x) {
    double r = __builtin_amdgcn_rsq(x);
    r = r * (1.5 - 0.5 * x * r * r);
    r = r * (1.5 - 0.5 * x * r * r);
    return r;
}
__device__ __forceinline__ double fast_rcp(double x) {
    double r = __builtin_amdgcn_rcp(x);
    r = r * (2.0 - x * r);
    r = r * (2.0 - x * r);
    return r;
}
__device__ __forceinline__ double fast_sqrt(double x) { return x * fast_rsqrt(x); }

// density = (L L^T + 2e-6 I) / (||L||_F^2 + 1.6e-5 + 1e-6), diag(L) clamped >= 1e-4.
// Inputs exact fp32; all products/sums fp64 (density errors perturb eigenvalues ABSOLUTELY,
// so this stage must stay accurate). emb rows are 144 B = 9 aligned float4.
template <bool ACCUM>
__device__ __forceinline__ void add_density(const float* __restrict__ p, double (&dst)[TRIL]) {
    float Lf[TRIL];
    const float4* p4 = (const float4*)p;
    #pragma unroll
    for (int i = 0; i < 9; ++i) {
        float4 v = p4[i];
        Lf[4*i+0] = v.x; Lf[4*i+1] = v.y; Lf[4*i+2] = v.z; Lf[4*i+3] = v.w;
    }
    #pragma unroll
    for (int d = 0; d < DIM; ++d) Lf[tri(d, d)] = fmaxf(Lf[tri(d, d)], 1.0e-4f);

    double tr = 1.6e-5;
    #pragma unroll
    for (int i = 0; i < TRIL; ++i) { double v = (double)Lf[i]; tr += v * v; }
    double inv = fast_rcp(tr + 1.0e-6);

    #pragma unroll
    for (int i = 0; i < DIM; ++i) {
        #pragma unroll
        for (int j = 0; j <= i; ++j) {
            double sum = (i == j) ? 2.0e-6 : 0.0;
            #pragma unroll
            for (int k = 0; k <= j; ++k) sum += (double)Lf[tri(i, k)] * (double)Lf[tri(j, k)];
            if (ACCUM) dst[tri(i, j)] += sum * inv;
            else       dst[tri(i, j)]  = sum * inv;
        }
    }
}

// in-place fp64 Cholesky of sym-36 (lower). Stays fp64: chol backward error is
// absolute wrt ||A|| -> would leak absolute eigenvalue error in fp32.
__device__ __forceinline__ void chol36(double (&M)[TRIL]) {
    #pragma unroll
    for (int j = 0; j < DIM; ++j) {
        double d = M[tri(j, j)];
        #pragma unroll
        for (int k = 0; k < j; ++k) d -= M[tri(j, k)] * M[tri(j, k)];
        d = fmax(d, 1.0e-30);
        double invd = fast_rsqrt(d);
        M[tri(j, j)] = d * invd;
        #pragma unroll
        for (int i = j + 1; i < DIM; ++i) {
            double v = M[tri(i, j)];
            #pragma unroll
            for (int k = 0; k < j; ++k) v -= M[tri(i, k)] * M[tri(j, k)];
            M[tri(i, j)] = v * invd;
        }
    }
}

// 8 lanes cooperate per batch element (2 quads, redundant past the reduce).
// Within each quad, lane g owns G columns (2g, 2g+1) for the systolic Jacobi.
// Rationale: 4 lanes/elem = 1024 waves = 1 wave/SIMD -> pure latency-bound
// (VALUBusy ~4%). 8 lanes/elem doubles resident waves (2/SIMD) so the serial
// fp64 chol / Jacobi dependency chains of one wave overlap the other's stalls.
__global__ void __launch_bounds__(64, 2)
qcbow_kernel(const int* __restrict__ contexts,  // [NB, SEQ]
             const int* __restrict__ targets,   // [NB]
             const float* __restrict__ emb,     // [100000, TRIL]
             float* __restrict__ out)           // [NB]
{
    const int tid = blockIdx.x * 64 + threadIdx.x;
    const int b  = tid >> 3;            // 8 lanes per element
    const int g8 = threadIdx.x & 7;     // lane within the 8-lane group
    const int g  = threadIdx.x & 3;     // lane within quad (Jacobi layout)

    // ---- hoist all token ids: two independent load chains start immediately ----
    const int tok0 = contexts[b * SEQ + g8];                       // s = g8   (0..7)
    const int tok1 = (g8 < 2) ? contexts[b * SEQ + 8 + g8] : 0;    // s = 8,9 on lanes 0,1
    const int tgt  = targets[b];

    // ---- phase 1: partial context density (<=2 tokens/lane vs 3 at 4-lane split) ----
    double A[TRIL];
    #pragma unroll
    for (int i = 0; i < TRIL; ++i) A[i] = 0.0;
    float cntf = 0.0f;
    if (tok0 != 0) { add_density<true>(emb + (size_t)tok0 * TRIL, A); cntf += 1.0f; }
    if (tok1 != 0) { add_density<true>(emb + (size_t)tok1 * TRIL, A); cntf += 1.0f; }

    // ---- sigma (target density), redundant on all 8 lanes (same cachelines) ----
    double W[TRIL];
    add_density<false>(emb + (size_t)tgt * TRIL, W);

    // ---- allreduce A,cnt over the 8-lane group: DPP xor1, xor2 + ds_swizzle xor4 ----
    #pragma unroll
    for (int i = 0; i < TRIL; ++i) A[i] += dperm<0xB1>(A[i]);   // xor 1
    cntf += fperm<0xB1>(cntf);
    #pragma unroll
    for (int i = 0; i < TRIL; ++i) A[i] += dperm<0x4E>(A[i]);   // xor 2
    cntf += fperm<0x4E>(cntf);
    #pragma unroll
    for (int i = 0; i < TRIL; ++i) A[i] += dswz4(A[i]);         // xor 4 (cross-quad)
    cntf += fswz4(cntf);

    // W <- chol(sigma)
    chol36(W);

    // ---- A <- rho_ctx + 1e-6 I ; A <- Lc = chol(A) ----
    double invc = fast_rcp((double)cntf);
    #pragma unroll
    for (int i = 0; i < TRIL; ++i) A[i] *= invc;
    #pragma unroll
    for (int d = 0; d < DIM; ++d) A[tri(d, d)] += 1.0e-6;
    chol36(A);

    // ---- G = Lc^T * W in fp64; lane g takes columns (2g, 2g+1), cast to fp32.
    // eig((rho+eps I) sigma) = eig(G G^T) = sing(G)^2 = final column norms^2.
    double wa[DIM], wb[DIM];
#define PICKW(JA, JB)                                                              \
    {                                                                              \
        _Pragma("unroll")                                                          \
        for (int k = 0; k < DIM; ++k) wa[k] = (k >= (JA)) ? W[tri(k, (JA))] : 0.0; \
        _Pragma("unroll")                                                          \
        for (int k = 0; k < DIM; ++k) wb[k] = (k >= (JB)) ? W[tri(k, (JB))] : 0.0; \
    }
    switch (g) {
        case 0: PICKW(0, 1); break;
        case 1: PICKW(2, 3); break;
        case 2: PICKW(4, 5); break;
        default: PICKW(6, 7); break;
    }
#undef PICKW

    float a[DIM], bb[DIM];   // my two G columns, fp32 (rotation errors are column-relative)
    #pragma unroll
    for (int i = 0; i < DIM; ++i) {
        double sa = 0.0, sb = 0.0;
        #pragma unroll
        for (int k = i; k < DIM; ++k) {
            double lk = A[tri(k, i)];      // (Lc^T)[i][k]
            sa += lk * wa[k];
            sb += lk * wb[k];
        }
        a[i] = (float)sa; bb[i] = (float)sb;
    }

    // ---- systolic one-sided Jacobi (Brent-Luk), fp32, DPP exchange.
    // Exchange cycle covers all 28 pairs in 7 rounds (verified R3, absmax at floor).
    // Convergence: z^2 <= 1e-12*x*y (cluster-safe) OR z^2 <= 1e-12*(x-y)^2
    // (fp32-angle residual ~1e-7*|x-y|; implies dLambda <= 1e-12*|x-y| -- harmless).
    for (int sweep = 0; sweep < 8; ++sweep) {
        bool conv = true;
        #pragma unroll
        for (int r = 0; r < 7; ++r) {
            float x = 0.0f, y = 0.0f, z = 0.0f;
            #pragma unroll
            for (int k = 0; k < DIM; ++k) {
                x = fmaf(a[k], a[k], x);
                y = fmaf(bb[k], bb[k], y);
                z = fmaf(a[k], bb[k], z);
            }
            float z2 = z * z;
            float d  = x - y;
            if (z2 > 1.0e-12f * x * y && z2 > 1.0e-12f * d * d) conv = false;
            if (z2 > 1.0e-16f * x * y) {   // skip pure-noise rotations; guards rcp(0)
                float tau = -d * (0.5f * __builtin_amdgcn_rcpf(z));
                float t = __builtin_amdgcn_rcpf(fabsf(tau) + sqrtf(fmaf(tau, tau, 1.0f)));
                t = (tau >= 0.0f) ? t : -t;
                float c = __builtin_amdgcn_rsqf(fmaf(t, t, 1.0f));
                float s = t * c;
                #pragma unroll
                for (int k = 0; k < DIM; ++k) {
                    float na = c * a[k] - s * bb[k];
                    float nb = s * a[k] + c * bb[k];
                    a[k] = na; bb[k] = nb;
                }
            }
            // systolic exchange, single-cycle DPP quad perms:
            #pragma unroll
            for (int k = 0; k < DIM; ++k) {
                float olda = a[k];
                float sa = (g == 0) ? bb[k] : a[k];
                float ta = fperm<0x93>(sa);       // from lane (g+3)&3
                float tb = fperm<0x39>(bb[k]);    // from lane (g+1)&3
                a[k]  = (g == 0) ? olda : ta;
                bb[k] = (g == 3) ? olda : tb;
            }
        }
        if (sweep >= 2 && __all(conv)) break;
    }

    // ---- fidelity: lambda_i = ||col_i||^2 (fp64 norms of fp32 cols: relative-accurate) ----
    double xn = 0.0, yn = 0.0;
    #pragma unroll
    for (int k = 0; k < DIM; ++k) {
        xn += (double)a[k] * (double)a[k];
        yn += (double)bb[k] * (double)bb[k];
    }
    double fp = fast_sqrt(xn + 1.0e-6) + fast_sqrt(yn + 1.0e-6);
    fp += dperm<0xB1>(fp);
    fp += dperm<0x4E>(fp);
    if (g8 == 0) {
        double f = fmin(fp, 1.0);
        f = fmax(f, 1.0e-8);
        out[b] = (float)(-log(f));
    }
}

extern "C" void kernel_launch(void* const* d_in, const int* in_sizes, int n_in,
                              void* d_out, int out_size, void* d_ws, size_t ws_size,
                              hipStream_t stream) {
    const int*   contexts = (const int*)d_in[0];
    const int*   targets  = (const int*)d_in[1];
    const float* emb      = (const float*)d_in[2];
    float*       out      = (float*)d_out;

    qcbow_kernel<<<dim3(NB * 8 / 64), dim3(64), 0, stream>>>(contexts, targets, emb, out);
}

// Round 2
// 84.825 us; speedup vs baseline: 1.1188x; 1.1188x over previous
//
#include <hip/hip_runtime.h>
#include <math.h>

#define NB   16384
#define SEQ  10
#define DIM  8
#define TRIL 36

__device__ __forceinline__ constexpr int tri(int r, int c) { return r * (r + 1) / 2 + c; } // r >= c

// ---- DPP quad-perm helpers (VALU cross-lane within each aligned quad) ----
// ctrl byte = s0 | s1<<2 | s2<<4 | s3<<6 : lane i reads from quad-lane s_i.
template <int CTRL>
__device__ __forceinline__ float fperm(float v) {
    return __int_as_float(__builtin_amdgcn_mov_dpp(__float_as_int(v), CTRL, 0xf, 0xf, true));
}
template <int CTRL>
__device__ __forceinline__ double dperm(double v) {
    long long u = __double_as_longlong(v);
    int lo = (int)(u & 0xffffffffLL);
    int hi = (int)(u >> 32);
    lo = __builtin_amdgcn_mov_dpp(lo, CTRL, 0xf, 0xf, true);
    hi = __builtin_amdgcn_mov_dpp(hi, CTRL, 0xf, 0xf, true);
    return __longlong_as_double(((long long)hi << 32) | (long long)(unsigned)lo);
}
// quad perms: XOR1=[1,0,3,2]=0xB1, XOR2=[2,3,0,1]=0x4E,
// RECV_A: from (g+3)&3 = [3,0,1,2] = 0x93 ; RECV_B: from (g+1)&3 = [1,2,3,0] = 0x39.

// fp64 rsqrt/rcp via HW seed + Newton (no fp64 div/sqrt chains)
__device__ __forceinline__ double fast_rsqrt(double x) {
    double r = __builtin_amdgcn_rsq(x);
    r = r * (1.5 - 0.5 * x * r * r);
    r = r * (1.5 - 0.5 * x * r * r);
    return r;
}
__device__ __forceinline__ double fast_rcp(double x) {
    double r = __builtin_amdgcn_rcp(x);
    r = r * (2.0 - x * r);
    r = r * (2.0 - x * r);
    return r;
}
__device__ __forceinline__ double fast_sqrt(double x) { return x * fast_rsqrt(x); }

// density = (L L^T + 2e-6 I) / (||L||_F^2 + 1.6e-5 + 1e-6), diag(L) clamped >= 1e-4.
// Inputs exact fp32; all products/sums fp64 (density errors perturb eigenvalues ABSOLUTELY,
// so this stage must stay accurate). emb rows are 144 B = 9 aligned float4.
template <bool ACCUM>
__device__ __forceinline__ void add_density(const float* __restrict__ p, double (&dst)[TRIL]) {
    float Lf[TRIL];
    const float4* p4 = (const float4*)p;
    #pragma unroll
    for (int i = 0; i < 9; ++i) {
        float4 v = p4[i];
        Lf[4*i+0] = v.x; Lf[4*i+1] = v.y; Lf[4*i+2] = v.z; Lf[4*i+3] = v.w;
    }
    #pragma unroll
    for (int d = 0; d < DIM; ++d) Lf[tri(d, d)] = fmaxf(Lf[tri(d, d)], 1.0e-4f);

    double tr = 1.6e-5;
    #pragma unroll
    for (int i = 0; i < TRIL; ++i) { double v = (double)Lf[i]; tr += v * v; }
    double inv = fast_rcp(tr + 1.0e-6);

    #pragma unroll
    for (int i = 0; i < DIM; ++i) {
        #pragma unroll
        for (int j = 0; j <= i; ++j) {
            double sum = (i == j) ? 2.0e-6 : 0.0;
            #pragma unroll
            for (int k = 0; k <= j; ++k) sum += (double)Lf[tri(i, k)] * (double)Lf[tri(j, k)];
            if (ACCUM) dst[tri(i, j)] += sum * inv;
            else       dst[tri(i, j)]  = sum * inv;
        }
    }
}

// in-place fp64 Cholesky of sym-36 (lower). Stays fp64: chol backward error is
// absolute wrt ||A|| -> would leak absolute eigenvalue error in fp32.
__device__ __forceinline__ void chol36(double (&M)[TRIL]) {
    #pragma unroll
    for (int j = 0; j < DIM; ++j) {
        double d = M[tri(j, j)];
        #pragma unroll
        for (int k = 0; k < j; ++k) d -= M[tri(j, k)] * M[tri(j, k)];
        d = fmax(d, 1.0e-30);
        double invd = fast_rsqrt(d);
        M[tri(j, j)] = d * invd;
        #pragma unroll
        for (int i = j + 1; i < DIM; ++i) {
            double v = M[tri(i, j)];
            #pragma unroll
            for (int k = 0; k < j; ++k) v -= M[tri(i, k)] * M[tri(j, k)];
            M[tri(i, j)] = v * invd;
        }
    }
}

// 4 lanes cooperate per batch element. Lane g owns G columns (2g, 2g+1).
// Work split (R2): 3 density slots (not 4) -- lanes 0,1 do ctx tokens {g, g+4, 8+g},
// lanes 2,3 do ctx {g, g+4} + the TARGET density in slot 3. After the quad allreduce
// of A, ONE chol36 factors rho_ctx (lanes 0,1) and sigma (lanes 2,3) simultaneously
// (identical straight-line code, different data -> no divergence); results are
// redistributed with DPP xor2. Saves one add_density + one chol36 per wave
// (kernel is ~90% issue-bound at 1 wave/SIMD; R1 showed forcing 2 waves/SIMD spills).
__global__ void __launch_bounds__(64)
qcbow_kernel(const int* __restrict__ contexts,  // [NB, SEQ]
             const int* __restrict__ targets,   // [NB]
             const float* __restrict__ emb,     // [100000, TRIL]
             float* __restrict__ out)           // [NB]
{
    const int tid = blockIdx.x * 64 + threadIdx.x;
    const int b = tid >> 2;
    const int g = threadIdx.x & 3;
    const bool isLo = (g < 2);

    // ---- token ids (slot3: lanes 0,1 -> ctx s=8+g ; lanes 2,3 -> target; no OOB reads) ----
    const int t1 = contexts[b * SEQ + g];
    const int t2 = contexts[b * SEQ + g + 4];
    const int* p3 = isLo ? (contexts + b * SEQ + 8 + g) : (targets + b);
    const int t3 = *p3;

    // ---- slots 1,2: partial context density ----
    double A[TRIL];
    #pragma unroll
    for (int i = 0; i < TRIL; ++i) A[i] = 0.0;
    float cntf = 0.0f;
    if (t1 != 0) { add_density<true>(emb + (size_t)t1 * TRIL, A); cntf += 1.0f; }
    if (t2 != 0) { add_density<true>(emb + (size_t)t2 * TRIL, A); cntf += 1.0f; }

    // ---- slot 3: lanes 0,1 compute ctx density into W then fold into A;
    //             lanes 2,3 compute sigma (target density) into W and keep it. ----
    double W[TRIL];
    add_density<false>(emb + (size_t)t3 * TRIL, W);
    if (isLo && t3 != 0) {
        cntf += 1.0f;
        #pragma unroll
        for (int i = 0; i < TRIL; ++i) A[i] += W[i];
    }

    // ---- allreduce A,cnt over the quad via DPP (VALU, no DS latency) ----
    #pragma unroll
    for (int i = 0; i < TRIL; ++i) A[i] += dperm<0xB1>(A[i]);   // xor 1
    cntf += fperm<0xB1>(cntf);
    #pragma unroll
    for (int i = 0; i < TRIL; ++i) A[i] += dperm<0x4E>(A[i]);   // xor 2
    cntf += fperm<0x4E>(cntf);

    // ---- A <- rho_ctx + 1e-6 I ----
    double invc = fast_rcp((double)cntf);
    #pragma unroll
    for (int i = 0; i < TRIL; ++i) A[i] *= invc;
    #pragma unroll
    for (int d = 0; d < DIM; ++d) A[tri(d, d)] += 1.0e-6;

    // ---- merge: lanes 0,1 factor rho_ctx; lanes 2,3 factor sigma. ONE chol for both. ----
    #pragma unroll
    for (int i = 0; i < TRIL; ++i) A[i] = isLo ? A[i] : W[i];
    chol36(A);   // lanes 0,1: Lc ; lanes 2,3: Lw

    // ---- extract Lw columns. Lane g needs cols (2g, 2g+1) of Lw.
    // lanes 2,3 extract their own cols into (wa,wb) and their partner's (lane g&1)
    // cols into (pa,pb); one DPP xor2 ships (pa,pb) to lanes 0,1. ----
    double wa[DIM], wb[DIM], pa[DIM], pb[DIM];
    #pragma unroll
    for (int k = 0; k < DIM; ++k) { wa[k] = 0.0; wb[k] = 0.0; pa[k] = 0.0; pb[k] = 0.0; }
#define EXTRACT(dst_a, dst_b, JA, JB)                                                  \
    {                                                                                  \
        _Pragma("unroll")                                                              \
        for (int k = 0; k < DIM; ++k) dst_a[k] = (k >= (JA)) ? A[tri(k, (JA))] : 0.0;  \
        _Pragma("unroll")                                                              \
        for (int k = 0; k < DIM; ++k) dst_b[k] = (k >= (JB)) ? A[tri(k, (JB))] : 0.0;  \
    }
    switch (g) {
        case 2: EXTRACT(pa, pb, 0, 1); EXTRACT(wa, wb, 4, 5); break;
        case 3: EXTRACT(pa, pb, 2, 3); EXTRACT(wa, wb, 6, 7); break;
        default: break;
    }
#undef EXTRACT
    #pragma unroll
    for (int k = 0; k < DIM; ++k) {
        double qa = dperm<0x4E>(pa[k]);   // lane0 <- lane2's cols(0,1); lane1 <- lane3's (2,3)
        double qb = dperm<0x4E>(pb[k]);
        wa[k] = isLo ? qa : wa[k];
        wb[k] = isLo ? qb : wb[k];
    }
    // broadcast Lc (lanes 0,1) to lanes 2,3 -- AFTER the Lw extraction above
    #pragma unroll
    for (int i = 0; i < TRIL; ++i) {
        double t = dperm<0x4E>(A[i]);
        A[i] = isLo ? A[i] : t;
    }

    // ---- G = Lc^T * Lw in fp64; lane g holds columns (2g, 2g+1), cast to fp32.
    // eig((rho+eps I) sigma) = eig(G G^T) = sing(G)^2 = final column norms^2.
    float a[DIM], bb[DIM];   // my two G columns, fp32 (rotation errors are column-relative)
    #pragma unroll
    for (int i = 0; i < DIM; ++i) {
        double sa = 0.0, sb = 0.0;
        #pragma unroll
        for (int k = i; k < DIM; ++k) {
            double lk = A[tri(k, i)];      // (Lc^T)[i][k]
            sa += lk * wa[k];
            sb += lk * wb[k];
        }
        a[i] = (float)sa; bb[i] = (float)sb;
    }

    // ---- systolic one-sided Jacobi (Brent-Luk), fp32, DPP exchange.
    // Exchange cycle covers all 28 pairs in 7 rounds (verified R3, absmax at floor).
    // Convergence: z^2 <= 1e-12*x*y (cluster-safe) OR z^2 <= 1e-12*(x-y)^2
    // (fp32-angle residual ~1e-7*|x-y|; implies dLambda <= 1e-12*|x-y| -- harmless).
    for (int sweep = 0; sweep < 8; ++sweep) {
        bool conv = true;
        #pragma unroll
        for (int r = 0; r < 7; ++r) {
            float x = 0.0f, y = 0.0f, z = 0.0f;
            #pragma unroll
            for (int k = 0; k < DIM; ++k) {
                x = fmaf(a[k], a[k], x);
                y = fmaf(bb[k], bb[k], y);
                z = fmaf(a[k], bb[k], z);
            }
            float z2 = z * z;
            float d  = x - y;
            if (z2 > 1.0e-12f * x * y && z2 > 1.0e-12f * d * d) conv = false;
            if (z2 > 1.0e-16f * x * y) {   // skip pure-noise rotations; guards rcp(0)
                float tau = -d * (0.5f * __builtin_amdgcn_rcpf(z));
                float t = __builtin_amdgcn_rcpf(fabsf(tau) + sqrtf(fmaf(tau, tau, 1.0f)));
                t = (tau >= 0.0f) ? t : -t;
                float c = __builtin_amdgcn_rsqf(fmaf(t, t, 1.0f));
                float s = t * c;
                #pragma unroll
                for (int k = 0; k < DIM; ++k) {
                    float na = c * a[k] - s * bb[k];
                    float nb = s * a[k] + c * bb[k];
                    a[k] = na; bb[k] = nb;
                }
            }
            // systolic exchange, single-cycle DPP quad perms:
            #pragma unroll
            for (int k = 0; k < DIM; ++k) {
                float olda = a[k];
                float sa = (g == 0) ? bb[k] : a[k];
                float ta = fperm<0x93>(sa);       // from lane (g+3)&3
                float tb = fperm<0x39>(bb[k]);    // from lane (g+1)&3
                a[k]  = (g == 0) ? olda : ta;
                bb[k] = (g == 3) ? olda : tb;
            }
        }
        if (sweep >= 2 && __all(conv)) break;
    }

    // ---- fidelity: lambda_i = ||col_i||^2 (fp64 norms of fp32 cols: relative-accurate) ----
    double xn = 0.0, yn = 0.0;
    #pragma unroll
    for (int k = 0; k < DIM; ++k) {
        xn += (double)a[k] * (double)a[k];
        yn += (double)bb[k] * (double)bb[k];
    }
    double fp = fast_sqrt(xn + 1.0e-6) + fast_sqrt(yn + 1.0e-6);
    fp += dperm<0xB1>(fp);
    fp += dperm<0x4E>(fp);
    if (g == 0) {
        double f = fmin(fp, 1.0);
        f = fmax(f, 1.0e-8);
        out[b] = (float)(-log(f));
    }
}

extern "C" void kernel_launch(void* const* d_in, const int* in_sizes, int n_in,
                              void* d_out, int out_size, void* d_ws, size_t ws_size,
                              hipStream_t stream) {
    const int*   contexts = (const int*)d_in[0];
    const int*   targets  = (const int*)d_in[1];
    const float* emb      = (const float*)d_in[2];
    float*       out      = (float*)d_out;

    qcbow_kernel<<<dim3(NB * 4 / 64), dim3(64), 0, stream>>>(contexts, targets, emb, out);
}

// Round 3
// 84.718 us; speedup vs baseline: 1.1202x; 1.0013x over previous
//
#include <hip/hip_runtime.h>
#include <math.h>

#define NB   16384
#define SEQ  10
#define DIM  8
#define TRIL 36

typedef float v2f __attribute__((ext_vector_type(2)));

__device__ __forceinline__ constexpr int tri(int r, int c) { return r * (r + 1) / 2 + c; } // r >= c

// ---- DPP quad-perm helpers (VALU cross-lane within each aligned quad) ----
// ctrl byte = s0 | s1<<2 | s2<<4 | s3<<6 : lane i reads from quad-lane s_i.
template <int CTRL>
__device__ __forceinline__ float fperm(float v) {
    return __int_as_float(__builtin_amdgcn_mov_dpp(__float_as_int(v), CTRL, 0xf, 0xf, true));
}
template <int CTRL>
__device__ __forceinline__ double dperm(double v) {
    long long u = __double_as_longlong(v);
    int lo = (int)(u & 0xffffffffLL);
    int hi = (int)(u >> 32);
    lo = __builtin_amdgcn_mov_dpp(lo, CTRL, 0xf, 0xf, true);
    hi = __builtin_amdgcn_mov_dpp(hi, CTRL, 0xf, 0xf, true);
    return __longlong_as_double(((long long)hi << 32) | (long long)(unsigned)lo);
}
// quad perms: XOR1=[1,0,3,2]=0xB1, XOR2=[2,3,0,1]=0x4E,
// RECV_A: from (g+3)&3 = [3,0,1,2] = 0x93 ; RECV_B: from (g+1)&3 = [1,2,3,0] = 0x39.

// fp64 rsqrt/rcp via HW seed + Newton (no fp64 div/sqrt chains)
__device__ __forceinline__ double fast_rsqrt(double x) {
    double r = __builtin_amdgcn_rsq(x);
    r = r * (1.5 - 0.5 * x * r * r);
    r = r * (1.5 - 0.5 * x * r * r);
    return r;
}
__device__ __forceinline__ double fast_rcp(double x) {
    double r = __builtin_amdgcn_rcp(x);
    r = r * (2.0 - x * r);
    r = r * (2.0 - x * r);
    return r;
}
__device__ __forceinline__ double fast_sqrt(double x) { return x * fast_rsqrt(x); }

// density = (L L^T + 2e-6 I) / (||L||_F^2 + 1.6e-5 + 1e-6), diag(L) clamped >= 1e-4.
// Inputs exact fp32; all products/sums fp64 (density errors perturb eigenvalues ABSOLUTELY,
// so this stage must stay accurate; per-token inv is NOT uniform across the ctx sum, so
// it stays fp64 too). emb rows are 144 B = 9 aligned float4.
template <bool ACCUM>
__device__ __forceinline__ void add_density(const float* __restrict__ p, double (&dst)[TRIL]) {
    float Lf[TRIL];
    const float4* p4 = (const float4*)p;
    #pragma unroll
    for (int i = 0; i < 9; ++i) {
        float4 v = p4[i];
        Lf[4*i+0] = v.x; Lf[4*i+1] = v.y; Lf[4*i+2] = v.z; Lf[4*i+3] = v.w;
    }
    #pragma unroll
    for (int d = 0; d < DIM; ++d) Lf[tri(d, d)] = fmaxf(Lf[tri(d, d)], 1.0e-4f);

    double tr = 1.6e-5;
    #pragma unroll
    for (int i = 0; i < TRIL; ++i) { double v = (double)Lf[i]; tr += v * v; }
    double inv = fast_rcp(tr + 1.0e-6);

    #pragma unroll
    for (int i = 0; i < DIM; ++i) {
        #pragma unroll
        for (int j = 0; j <= i; ++j) {
            double sum = (i == j) ? 2.0e-6 : 0.0;
            #pragma unroll
            for (int k = 0; k <= j; ++k) sum += (double)Lf[tri(i, k)] * (double)Lf[tri(j, k)];
            if (ACCUM) dst[tri(i, j)] += sum * inv;
            else       dst[tri(i, j)]  = sum * inv;
        }
    }
}

// in-place fp64 Cholesky of sym-36 (lower). Stays fp64: chol backward error is
// absolute wrt ||A|| -> would leak absolute eigenvalue error in fp32.
__device__ __forceinline__ void chol36(double (&M)[TRIL]) {
    #pragma unroll
    for (int j = 0; j < DIM; ++j) {
        double d = M[tri(j, j)];
        #pragma unroll
        for (int k = 0; k < j; ++k) d -= M[tri(j, k)] * M[tri(j, k)];
        d = fmax(d, 1.0e-30);
        double invd = fast_rsqrt(d);
        M[tri(j, j)] = d * invd;
        #pragma unroll
        for (int i = j + 1; i < DIM; ++i) {
            double v = M[tri(i, j)];
            #pragma unroll
            for (int k = 0; k < j; ++k) v -= M[tri(i, k)] * M[tri(j, k)];
            M[tri(i, j)] = v * invd;
        }
    }
}

// 4 lanes cooperate per batch element. Lane g owns G columns (2g, 2g+1).
// Work split (R2): 3 density slots -- lanes 0,1 do ctx tokens {g, g+4, 8+g},
// lanes 2,3 do ctx {g, g+4} + the TARGET density in slot 3. ONE chol36 factors
// rho_ctx (lanes 0,1) and sigma (lanes 2,3) simultaneously; DPP redistributes.
// R3: invc scaling folded out of the matrix (chol(c*A)=sqrt(c)*chol(A); applied
// once in the final column norms), and the fp32 Jacobi packed into v_pk_fma_f32
// via 2-wide ext vectors (dots 24->12 ops, rotations 32->16 ops per round).
__global__ void __launch_bounds__(64)
qcbow_kernel(const int* __restrict__ contexts,  // [NB, SEQ]
             const int* __restrict__ targets,   // [NB]
             const float* __restrict__ emb,     // [100000, TRIL]
             float* __restrict__ out)           // [NB]
{
    const int tid = blockIdx.x * 64 + threadIdx.x;
    const int b = tid >> 2;
    const int g = threadIdx.x & 3;
    const bool isLo = (g < 2);

    // ---- token ids (slot3: lanes 0,1 -> ctx s=8+g ; lanes 2,3 -> target; no OOB reads) ----
    const int t1 = contexts[b * SEQ + g];
    const int t2 = contexts[b * SEQ + g + 4];
    const int* p3 = isLo ? (contexts + b * SEQ + 8 + g) : (targets + b);
    const int t3 = *p3;

    // ---- slots 1,2: partial context density ----
    double A[TRIL];
    #pragma unroll
    for (int i = 0; i < TRIL; ++i) A[i] = 0.0;
    float cntf = 0.0f;
    if (t1 != 0) { add_density<true>(emb + (size_t)t1 * TRIL, A); cntf += 1.0f; }
    if (t2 != 0) { add_density<true>(emb + (size_t)t2 * TRIL, A); cntf += 1.0f; }

    // ---- slot 3: lanes 0,1 compute ctx density into W then fold into A;
    //             lanes 2,3 compute sigma (target density) into W and keep it. ----
    double W[TRIL];
    add_density<false>(emb + (size_t)t3 * TRIL, W);
    if (isLo && t3 != 0) {
        cntf += 1.0f;
        #pragma unroll
        for (int i = 0; i < TRIL; ++i) A[i] += W[i];
    }

    // ---- allreduce A,cnt over the quad via DPP (VALU, no DS latency) ----
    #pragma unroll
    for (int i = 0; i < TRIL; ++i) A[i] += dperm<0xB1>(A[i]);   // xor 1
    cntf += fperm<0xB1>(cntf);
    #pragma unroll
    for (int i = 0; i < TRIL; ++i) A[i] += dperm<0x4E>(A[i]);   // xor 2
    cntf += fperm<0x4E>(cntf);

    // ---- R3: do NOT scale A by invc. chol(invc*(A + 1e-6*cnt*I)) = sqrt(invc)*chol(...);
    // the sqrt(invc) factor is applied once in the final column norms. ----
    const double invc = fast_rcp((double)cntf);
    const double diagAdd = 1.0e-6 * (double)cntf;
    #pragma unroll
    for (int d = 0; d < DIM; ++d) A[tri(d, d)] += diagAdd;

    // ---- merge: lanes 0,1 factor (unscaled) rho_ctx; lanes 2,3 factor sigma. ----
    #pragma unroll
    for (int i = 0; i < TRIL; ++i) A[i] = isLo ? A[i] : W[i];
    chol36(A);   // lanes 0,1: Lc*sqrt(cnt) ; lanes 2,3: Lw

    // ---- extract Lw columns. Lane g needs cols (2g, 2g+1) of Lw.
    // lanes 2,3 extract their own cols into (wa,wb) and their partner's (lane g&1)
    // cols into (pa,pb); one DPP xor2 ships (pa,pb) to lanes 0,1. ----
    double wa[DIM], wb[DIM], pa[DIM], pb[DIM];
    #pragma unroll
    for (int k = 0; k < DIM; ++k) { wa[k] = 0.0; wb[k] = 0.0; pa[k] = 0.0; pb[k] = 0.0; }
#define EXTRACT(dst_a, dst_b, JA, JB)                                                  \
    {                                                                                  \
        _Pragma("unroll")                                                              \
        for (int k = 0; k < DIM; ++k) dst_a[k] = (k >= (JA)) ? A[tri(k, (JA))] : 0.0;  \
        _Pragma("unroll")                                                              \
        for (int k = 0; k < DIM; ++k) dst_b[k] = (k >= (JB)) ? A[tri(k, (JB))] : 0.0;  \
    }
    switch (g) {
        case 2: EXTRACT(pa, pb, 0, 1); EXTRACT(wa, wb, 4, 5); break;
        case 3: EXTRACT(pa, pb, 2, 3); EXTRACT(wa, wb, 6, 7); break;
        default: break;
    }
#undef EXTRACT
    #pragma unroll
    for (int k = 0; k < DIM; ++k) {
        double qa = dperm<0x4E>(pa[k]);   // lane0 <- lane2's cols(0,1); lane1 <- lane3's (2,3)
        double qb = dperm<0x4E>(pb[k]);
        wa[k] = isLo ? qa : wa[k];
        wb[k] = isLo ? qb : wb[k];
    }
    // broadcast Lc (lanes 0,1) to lanes 2,3 -- AFTER the Lw extraction above
    #pragma unroll
    for (int i = 0; i < TRIL; ++i) {
        double t = dperm<0x4E>(A[i]);
        A[i] = isLo ? A[i] : t;
    }

    // ---- G = Lc^T * Lw in fp64; lane g holds columns (2g, 2g+1), cast to fp32 pairs.
    // eig((rho+eps I) sigma) = eig(G G^T) = sing(G)^2 = final column norms^2 (x invc). ----
    v2f a2[4], b2[4];   // my two G columns, fp32 packed (rotation errors are column-relative)
    #pragma unroll
    for (int i = 0; i < DIM; ++i) {
        double sa = 0.0, sb = 0.0;
        #pragma unroll
        for (int k = i; k < DIM; ++k) {
            double lk = A[tri(k, i)];      // (Lc^T)[i][k]
            sa += lk * wa[k];
            sb += lk * wb[k];
        }
        if (i & 1) { a2[i >> 1].y = (float)sa; b2[i >> 1].y = (float)sb; }
        else       { a2[i >> 1].x = (float)sa; b2[i >> 1].x = (float)sb; }
    }

    // ---- systolic one-sided Jacobi (Brent-Luk), fp32 packed (v_pk_fma_f32), DPP exchange.
    // Exchange cycle covers all 28 pairs in 7 rounds (verified R3, absmax at floor).
    // Convergence: z^2 <= 1e-12*x*y (cluster-safe) OR z^2 <= 1e-12*(x-y)^2; all
    // thresholds are relative -> invariant under the deferred invc scaling. ----
    for (int sweep = 0; sweep < 8; ++sweep) {
        bool conv = true;
        #pragma unroll
        for (int r = 0; r < 7; ++r) {
            v2f xv = a2[0] * a2[0];
            v2f yv = b2[0] * b2[0];
            v2f zv = a2[0] * b2[0];
            #pragma unroll
            for (int k = 1; k < 4; ++k) {
                xv = __builtin_elementwise_fma(a2[k], a2[k], xv);
                yv = __builtin_elementwise_fma(b2[k], b2[k], yv);
                zv = __builtin_elementwise_fma(a2[k], b2[k], zv);
            }
            float x = xv.x + xv.y;
            float y = yv.x + yv.y;
            float z = zv.x + zv.y;
            float z2 = z * z;
            float d  = x - y;
            if (z2 > 1.0e-12f * x * y && z2 > 1.0e-12f * d * d) conv = false;
            if (z2 > 1.0e-16f * x * y) {   // skip pure-noise rotations; guards rcp(0)
                float tau = -d * (0.5f * __builtin_amdgcn_rcpf(z));
                float t = __builtin_amdgcn_rcpf(fabsf(tau) + sqrtf(fmaf(tau, tau, 1.0f)));
                t = (tau >= 0.0f) ? t : -t;
                float c = __builtin_amdgcn_rsqf(fmaf(t, t, 1.0f));
                float s = t * c;
                v2f cv = {c, c}, sv = {s, s}, nsv = {-s, -s};
                #pragma unroll
                for (int k = 0; k < 4; ++k) {
                    v2f na = __builtin_elementwise_fma(nsv, b2[k], a2[k] * cv);
                    v2f nb = __builtin_elementwise_fma(sv,  a2[k], b2[k] * cv);
                    a2[k] = na; b2[k] = nb;
                }
            }
            // systolic exchange, single-cycle DPP quad perms (32-bit halves):
            #pragma unroll
            for (int k = 0; k < 4; ++k) {
                float a0 = a2[k].x, a1 = a2[k].y;
                float b0 = b2[k].x, b1 = b2[k].y;
                float sa0 = (g == 0) ? b0 : a0;
                float sa1 = (g == 0) ? b1 : a1;
                float ta0 = fperm<0x93>(sa0);     // from lane (g+3)&3
                float ta1 = fperm<0x93>(sa1);
                float tb0 = fperm<0x39>(b0);      // from lane (g+1)&3
                float tb1 = fperm<0x39>(b1);
                a2[k].x = (g == 0) ? a0 : ta0;
                a2[k].y = (g == 0) ? a1 : ta1;
                b2[k].x = (g == 3) ? a0 : tb0;
                b2[k].y = (g == 3) ? a1 : tb1;
            }
        }
        if (sweep >= 2 && __all(conv)) break;
    }

    // ---- fidelity: lambda_i = invc * ||col_i||^2 (fp64 norms of fp32 cols).
    // The +1e-6 sits INSIDE the sqrt, so apply invc before adding it. ----
    double xn = 0.0, yn = 0.0;
    #pragma unroll
    for (int k = 0; k < 4; ++k) {
        xn += (double)a2[k].x * (double)a2[k].x + (double)a2[k].y * (double)a2[k].y;
        yn += (double)b2[k].x * (double)b2[k].x + (double)b2[k].y * (double)b2[k].y;
    }
    double fp = fast_sqrt(invc * xn + 1.0e-6) + fast_sqrt(invc * yn + 1.0e-6);
    fp += dperm<0xB1>(fp);
    fp += dperm<0x4E>(fp);
    if (g == 0) {
        double f = fmin(fp, 1.0);
        f = fmax(f, 1.0e-8);
        out[b] = (float)(-log(f));
    }
}

extern "C" void kernel_launch(void* const* d_in, const int* in_sizes, int n_in,
                              void* d_out, int out_size, void* d_ws, size_t ws_size,
                              hipStream_t stream) {
    const int*   contexts = (const int*)d_in[0];
    const int*   targets  = (const int*)d_in[1];
    const float* emb      = (const float*)d_in[2];
    float*       out      = (float*)d_out;

    qcbow_kernel<<<dim3(NB * 4 / 64), dim3(64), 0, stream>>>(contexts, targets, emb, out);
}